// Round 1
// baseline (25411.311 us; speedup 1.0000x reference)
//
#include <hip/hip_runtime.h>

typedef unsigned short u16;
typedef __bf16 bf16x8 __attribute__((ext_vector_type(8)));
typedef float f32x4 __attribute__((ext_vector_type(4)));

#define EPSC 1e-6f

// ---------- helpers ----------
__device__ __forceinline__ float b2f(u16 x) { return __uint_as_float(((unsigned)x) << 16); }
__device__ __forceinline__ u16 f2b(float f) {
    unsigned u = __float_as_uint(f);
    unsigned r = (u + 0x7fffu + ((u >> 16) & 1u)) >> 16;
    return (u16)r;
}
__device__ __forceinline__ float bflo(unsigned u) { return __uint_as_float(u << 16); }
__device__ __forceinline__ float bfhi(unsigned u) { return __uint_as_float(u & 0xffff0000u); }
__device__ __forceinline__ float dot8(uint4 w, uint4 t) {
    float s;
    s  = bflo(w.x)*bflo(t.x) + bfhi(w.x)*bfhi(t.x);
    s += bflo(w.y)*bflo(t.y) + bfhi(w.y)*bfhi(t.y);
    s += bflo(w.z)*bflo(t.z) + bfhi(w.z)*bfhi(t.z);
    s += bflo(w.w)*bflo(t.w) + bfhi(w.w)*bfhi(t.w);
    return s;
}
__device__ __forceinline__ float softplusf(float x) {
    return fmaxf(x, 0.f) + log1pf(__expf(-fabsf(x)));
}

// ---------- conversion / transpose kernels ----------
__global__ void conv_x4(u16* __restrict__ dst, const float* __restrict__ x) {
    // dst[t][b][d] (bf16) = x[b][t][d] ; 4 elems per thread along d
    size_t i4 = (size_t)blockIdx.x * 256 + threadIdx.x;
    size_t o = i4 * 4;
    int d = (int)(o & 511);
    int b = (int)((o >> 9) & 255);
    int t = (int)(o >> 17);
    float4 v = *(const float4*)(x + ((size_t)b * 256 + t) * 512 + d);
    unsigned p0 = (unsigned)f2b(v.x) | ((unsigned)f2b(v.y) << 16);
    unsigned p1 = (unsigned)f2b(v.z) | ((unsigned)f2b(v.w) << 16);
    *(uint2*)(dst + o) = make_uint2(p0, p1);
}

__global__ void conv_f32_bf16(u16* __restrict__ dst, const float* __restrict__ src, int n) {
    int i = blockIdx.x * 256 + threadIdx.x;
    if (i < n) dst[i] = f2b(src[i]);
}

// dst [C][R] bf16 <- src rows R x cols C (row stride ld): dst[c*R+r] = src[r*ld+c]
__global__ void tr_conv(u16* __restrict__ dst, const float* __restrict__ src,
                        int R, int C, int ld) {
    int idx = blockIdx.x * 256 + threadIdx.x;
    if (idx >= R * C) return;
    int c = idx / R, r = idx % R;
    dst[idx] = f2b(src[(size_t)r * ld + c]);
}

// ---------- generic 128x128 bf16 MFMA GEMM ----------
enum { EPI_PARTIAL = 0, EPI_BF16_RELU = 1, EPI_BF16_NONE = 2,
       EPI_F32_RELU = 3, EPI_F32_SP = 4, EPI_F32_SIG = 5 };

template <int EPI>
__global__ __launch_bounds__(256)
void gemm128(const u16* __restrict__ A0, const u16* __restrict__ A1,
             int lda0, int lda1, int kSplit,
             const u16* __restrict__ Wt, int ldw,          // Wt[N][K]
             const float* __restrict__ bias,
             u16* __restrict__ Cb, float* __restrict__ Cf,
             int M, int N, int K, int kChunk) {
    __shared__ __align__(16) u16 As[128 * 72];
    __shared__ __align__(16) u16 Bs[128 * 72];
    const int tid = threadIdx.x;
    const int wid = tid >> 6, lane = tid & 63;
    const int wm = wid >> 1, wn = wid & 1;
    const int lr = lane & 15, lk = lane >> 4;
    const int m0 = blockIdx.y * 128, n0 = blockIdx.x * 128;
    const int kBeg = blockIdx.z * kChunk;
    const int rsub = lane >> 3;         // 0..7
    const int csub = (lane & 7) * 8;    // 0..56

    f32x4 acc[4][4];
#pragma unroll
    for (int i = 0; i < 4; i++)
#pragma unroll
        for (int j = 0; j < 4; j++) { f32x4 z = {0.f, 0.f, 0.f, 0.f}; acc[i][j] = z; }

    for (int kt = 0; kt < kChunk; kt += 64) {
        const int k0 = kBeg + kt;
        const u16* Ap; int kk, lda;
        if (k0 < kSplit) { Ap = A0; kk = k0; lda = lda0; }
        else             { Ap = A1; kk = k0 - kSplit; lda = lda1; }
        uint4 ra[4], rb[4];
#pragma unroll
        for (int i = 0; i < 4; i++) {
            const int q = wid * 4 + i;
            const int r = q * 8 + rsub;
            ra[i] = *(const uint4*)(Ap + (size_t)(m0 + r) * lda + kk + csub);
            rb[i] = *(const uint4*)(Wt + (size_t)(n0 + r) * ldw + k0 + csub);
        }
        __syncthreads();
#pragma unroll
        for (int i = 0; i < 4; i++) {
            const int q = wid * 4 + i;
            const int r = q * 8 + rsub;
            *(uint4*)&As[r * 72 + csub] = ra[i];
            *(uint4*)&Bs[r * 72 + csub] = rb[i];
        }
        __syncthreads();
#pragma unroll
        for (int s = 0; s < 2; s++) {
            bf16x8 af[4], bfr[4];
#pragma unroll
            for (int i = 0; i < 4; i++)
                af[i] = *(const bf16x8*)&As[(wm * 64 + i * 16 + lr) * 72 + s * 32 + lk * 8];
#pragma unroll
            for (int j = 0; j < 4; j++)
                bfr[j] = *(const bf16x8*)&Bs[(wn * 64 + j * 16 + lr) * 72 + s * 32 + lk * 8];
#pragma unroll
            for (int i = 0; i < 4; i++)
#pragma unroll
                for (int j = 0; j < 4; j++)
                    acc[i][j] = __builtin_amdgcn_mfma_f32_16x16x32_bf16(af[i], bfr[j], acc[i][j], 0, 0, 0);
        }
    }

    const int rowb = m0 + wm * 64, colb = n0 + wn * 64;
#pragma unroll
    for (int i = 0; i < 4; i++) {
#pragma unroll
        for (int j = 0; j < 4; j++) {
            const int col = colb + j * 16 + lr;
#pragma unroll
            for (int r = 0; r < 4; r++) {
                const int row = rowb + i * 16 + lk * 4 + r;
                float v = acc[i][j][r];
                if (EPI == EPI_PARTIAL) {
                    Cf[(size_t)blockIdx.z * ((size_t)M * N) + (size_t)row * N + col] = v;
                } else {
                    if (bias) v += bias[col];
                    if (EPI == EPI_BF16_RELU || EPI == EPI_F32_RELU) v = fmaxf(v, 0.f);
                    else if (EPI == EPI_F32_SP)  v = softplusf(v);
                    else if (EPI == EPI_F32_SIG) v = 1.f / (1.f + __expf(-v));
                    if (EPI == EPI_BF16_RELU || EPI == EPI_BF16_NONE) Cb[(size_t)row * N + col] = f2b(v);
                    else Cf[(size_t)row * N + col] = v;
                }
            }
        }
    }
}

// ---------- fused per-step kernel: reduce T12 partials -> zm/zs -> z -> GRU -> h_{t+1} ----------
__global__ __launch_bounds__(1024)
void step_zg(const float* __restrict__ Pbuf,                       // [8][256][2048]
             const float* __restrict__ em_b1, const float* __restrict__ es_b1,
             const u16* __restrict__ emW2T, const u16* __restrict__ esW2T,  // [128][1024]
             const float* __restrict__ em_b2, const float* __restrict__ es_b2,
             const float* __restrict__ eps_t,                      // [256][128]
             const u16* __restrict__ WihZT,                        // [3072][128]
             const u16* __restrict__ GIP_t,                        // [256][3072]
             const float* __restrict__ gbih, const float* __restrict__ gbhh,
             float* __restrict__ outZ, float* __restrict__ outMu, float* __restrict__ outStd,
             u16* __restrict__ Zbf_t, u16* __restrict__ Hnext) {
    __shared__ __align__(16) u16 T12L[2048];
    __shared__ float zmL[128], zsL[128];
    __shared__ __align__(16) u16 zbfL[128];
    const int b = blockIdx.x, tid = threadIdx.x;

    // phase 1: sum split-K partials, bias, relu -> bf16 row in LDS
    for (int c = tid; c < 2048; c += 1024) {
        float s = 0.f;
#pragma unroll
        for (int p = 0; p < 8; p++) s += Pbuf[((size_t)p * 256 + b) * 2048 + c];
        s += (c < 1024) ? em_b1[c] : es_b1[c - 1024];
        T12L[c] = f2b(fmaxf(s, 0.f));
    }
    __syncthreads();

    // phase 2: 256 outputs (zm_pre 0..127 | zs_pre 128..255), 4 threads per output
    {
        const int n = tid >> 2, q = tid & 3;
        const u16* wrow = (n < 128) ? (emW2T + (size_t)n * 1024) : (esW2T + (size_t)(n - 128) * 1024);
        const u16* trow = T12L + ((n < 128) ? 0 : 1024);
        const uint4* w4 = (const uint4*)(wrow + q * 256);
        const uint4* t4 = (const uint4*)(trow + q * 256);
        float s = 0.f;
#pragma unroll
        for (int i = 0; i < 32; i++) s += dot8(w4[i], t4[i]);
        s += __shfl_xor(s, 1);
        s += __shfl_xor(s, 2);
        if (q == 0) {
            if (n < 128) zmL[n] = fmaxf(s + em_b2[n], 0.f);
            else         zsL[n - 128] = softplusf(s + es_b2[n - 128]);
        }
    }
    __syncthreads();

    // phase 3: reparam sample + outputs
    if (tid < 128) {
        const float zm = zmL[tid], zs = zsL[tid];
        const float e = eps_t[(size_t)b * 128 + tid];
        const float z = zm + zs * e;
        const size_t o = (size_t)b * 128 + tid;
        outMu[o] = zm; outStd[o] = zs; outZ[o] = z;
        const u16 zb = f2b(z);
        Zbf_t[o] = zb; zbfL[tid] = zb;
    }
    __syncthreads();

    // phase 4: GRU gates (h_prev = 0 -> only b_hh contributes), one j per thread
    {
        const int j = tid;  // 0..1023
        const uint4* z4 = (const uint4*)zbfL;
        const uint4* wr = (const uint4*)(WihZT + (size_t)j * 128);
        const uint4* wu = (const uint4*)(WihZT + (size_t)(1024 + j) * 128);
        const uint4* wn4 = (const uint4*)(WihZT + (size_t)(2048 + j) * 128);
        float ar = 0.f, au = 0.f, an = 0.f;
#pragma unroll
        for (int i = 0; i < 16; i++) {
            const uint4 zv = z4[i];
            ar += dot8(wr[i], zv); au += dot8(wu[i], zv); an += dot8(wn4[i], zv);
        }
        const size_t gb = (size_t)b * 3072;
        const float gr = ar + b2f(GIP_t[gb + j]) + gbih[j] + gbhh[j];
        const float gu = au + b2f(GIP_t[gb + 1024 + j]) + gbih[1024 + j] + gbhh[1024 + j];
        float gn = an + b2f(GIP_t[gb + 2048 + j]) + gbih[2048 + j];
        const float r = 1.f / (1.f + __expf(-gr));
        const float u = 1.f / (1.f + __expf(-gu));
        gn += r * gbhh[2048 + j];
        const float e2 = __expf(-2.f * fabsf(gn));
        float th = (1.f - e2) / (1.f + e2);
        th = (gn < 0.f) ? -th : th;
        Hnext[(size_t)b * 1024 + j] = f2b((1.f - u) * th);
    }
}

// ---------- loss ----------
__global__ __launch_bounds__(256)
void loss_per_t(const float* __restrict__ x,    // [B][T][D]
                const float* __restrict__ xm,   // [T][B][D]
                const float* __restrict__ zm, const float* __restrict__ zs,  // [T][B][Z]
                const float* __restrict__ pm, const float* __restrict__ ps,
                float* __restrict__ kldT, float* __restrict__ nllT) {
    const int t = blockIdx.x, bb = threadIdx.x;
    float kld = 0.f, nll = 0.f;
    const size_t ozb = ((size_t)t * 256 + bb) * 128;
    for (int zz = 0; zz < 128; zz++) {
        const float qs = zs[ozb + zz], qm = zm[ozb + zz];
        const float pmv = pm[ozb + zz], psv = ps[ozb + zz];
        const float d = qm - pmv;
        kld += logf(psv + EPSC) - logf(qs + EPSC)
             + (qs * qs + d * d) / (2.f * psv * psv + EPSC) - 0.5f;
    }
    const size_t oxb = ((size_t)t * 256 + bb) * 512;
    const size_t oxi = ((size_t)bb * 256 + t) * 512;
    for (int dd = 0; dd < 512; dd++) {
        const float xv = x[oxi + dd];
        float m = xm[oxb + dd];
        m = fminf(fmaxf(m, 1e-6f), 1.f - 1e-6f);
        nll -= xv * logf(m) + (1.f - xv) * log1pf(-m);
    }
    __shared__ float sk[256], sn[256];
    sk[bb] = kld; sn[bb] = nll;
    __syncthreads();
    for (int s = 128; s > 0; s >>= 1) {
        if (bb < s) { sk[bb] += sk[bb + s]; sn[bb] += sn[bb + s]; }
        __syncthreads();
    }
    if (bb == 0) { kldT[t] = sk[0] / 256.f; nllT[t] = sn[0] / 256.f; }
}

__global__ __launch_bounds__(256)
void loss_final(const float* __restrict__ kldT, const float* __restrict__ nllT,
                float* __restrict__ out) {
    const int tid = threadIdx.x;
    __shared__ float s[256];
    s[tid] = kldT[tid] + nllT[tid];
    __syncthreads();
    for (int st = 128; st > 0; st >>= 1) {
        if (tid < st) s[tid] += s[tid + st];
        __syncthreads();
    }
    if (tid == 0) { out[0] = s[0]; out[1] = kldT[255]; out[2] = nllT[255]; }
}

// ---------- workspace layout (bytes) ----------
static constexpr size_t oPHIXWT  = 0;                       // [1024][512]
static constexpr size_t oWCATT   = oPHIXWT  + 1048576;      // [2048][2048]
static constexpr size_t oEMW2T   = oWCATT   + 8388608;      // [128][1024]
static constexpr size_t oESW2T   = oEMW2T   + 262144;
static constexpr size_t oWIHPHIT = oESW2T   + 262144;       // [3072][1024]
static constexpr size_t oWIHZT   = oWIHPHIT + 6291456;      // [3072][128]
static constexpr size_t oPMW1T   = oWIHZT   + 786432;       // [1024][1024]
static constexpr size_t oPMW2T   = oPMW1T   + 2097152;      // [128][1024]
static constexpr size_t oPSW1T   = oPMW2T   + 262144;
static constexpr size_t oPSW2T   = oPSW1T   + 2097152;
static constexpr size_t oDMW1T   = oPSW2T   + 262144;       // [1024][1152]
static constexpr size_t oDMW2T   = oDMW1T   + 2359296;      // [512][1024]
static constexpr size_t oXBFT    = oDMW2T   + 1048576;      // [T][B][D] bf16; later PM/PS f32
static constexpr size_t oPHI     = oXBFT    + 67108864;     // [T][B][H] bf16; later U1
static constexpr size_t oHS      = oPHI     + 134217728;    // [T+1][B][H] bf16
static constexpr size_t oZBF     = oHS      + 134742016;    // [T][B][Z] bf16
static constexpr size_t oGIPC    = oZBF     + 16777216;     // [32][B][3H] bf16 (chunk)
static constexpr size_t oPBUF    = oGIPC    + 50331648;     // [8][256][2048] f32
static constexpr size_t oKLDT    = oPBUF    + 16777216;
static constexpr size_t oNLLT    = oKLDT    + 1024;
static constexpr size_t WS_NEED  = oNLLT    + 1024;

static constexpr size_t NZ = (size_t)256 * 256 * 128;
static constexpr size_t O_Z  = 3;
static constexpr size_t O_MU = 3 + NZ;
static constexpr size_t O_STD = 3 + 2 * NZ;
static constexpr size_t O_XM = 3 + 3 * NZ;

extern "C" void kernel_launch(void* const* d_in, const int* in_sizes, int n_in,
                              void* d_out, int out_size, void* d_ws, size_t ws_size,
                              hipStream_t stream) {
    const float* x      = (const float*)d_in[0];
    const float* eps    = (const float*)d_in[1];
    const float* h0     = (const float*)d_in[2];
    const float* phix_w = (const float*)d_in[3];
    const float* phix_b = (const float*)d_in[4];
    const float* pm_w1  = (const float*)d_in[5];
    const float* pm_b1  = (const float*)d_in[6];
    const float* pm_w2  = (const float*)d_in[7];
    const float* pm_b2  = (const float*)d_in[8];
    const float* ps_w1  = (const float*)d_in[9];
    const float* ps_b1  = (const float*)d_in[10];
    const float* ps_w2  = (const float*)d_in[11];
    const float* ps_b2  = (const float*)d_in[12];
    const float* em_w1  = (const float*)d_in[13];
    const float* em_b1  = (const float*)d_in[14];
    const float* em_w2  = (const float*)d_in[15];
    const float* em_b2  = (const float*)d_in[16];
    const float* es_w1  = (const float*)d_in[17];
    const float* es_b1  = (const float*)d_in[18];
    const float* es_w2  = (const float*)d_in[19];
    const float* es_b2  = (const float*)d_in[20];
    const float* dm_w1  = (const float*)d_in[21];
    const float* dm_b1  = (const float*)d_in[22];
    const float* dm_w2  = (const float*)d_in[23];
    const float* dm_b2  = (const float*)d_in[24];
    const float* gwih   = (const float*)d_in[25];
    const float* gbih   = (const float*)d_in[26];
    const float* gbhh   = (const float*)d_in[27];
    float* out = (float*)d_out;

    if (ws_size < WS_NEED) return;
    char* w = (char*)d_ws;
    u16* phixWt  = (u16*)(w + oPHIXWT);
    u16* wcatT   = (u16*)(w + oWCATT);
    u16* emW2T   = (u16*)(w + oEMW2T);
    u16* esW2T   = (u16*)(w + oESW2T);
    u16* wihPhiT = (u16*)(w + oWIHPHIT);
    u16* wihZT   = (u16*)(w + oWIHZT);
    u16* pmW1T   = (u16*)(w + oPMW1T);
    u16* pmW2T   = (u16*)(w + oPMW2T);
    u16* psW1T   = (u16*)(w + oPSW1T);
    u16* psW2T   = (u16*)(w + oPSW2T);
    u16* dmW1T   = (u16*)(w + oDMW1T);
    u16* dmW2T   = (u16*)(w + oDMW2T);
    u16* XbfT    = (u16*)(w + oXBFT);
    u16* PHI     = (u16*)(w + oPHI);   // also U1 in phase C
    u16* HS      = (u16*)(w + oHS);
    u16* ZBF     = (u16*)(w + oZBF);
    u16* GIPC    = (u16*)(w + oGIPC);
    float* PBUF  = (float*)(w + oPBUF);
    float* PMbuf = (float*)(w + oXBFT);
    float* PSbuf = (float*)(w + oXBFT + 33554432);
    float* kldT  = (float*)(w + oKLDT);
    float* nllT  = (float*)(w + oNLLT);

    // ---- phase A: conversions / weight transposes / big precompute GEMMs ----
    conv_x4<<<32768, 256, 0, stream>>>(XbfT, x);
    conv_f32_bf16<<<1024, 256, 0, stream>>>(HS, h0, 262144);
    tr_conv<<<2048, 256, 0, stream>>>(phixWt, phix_w, 512, 1024, 1024);
    tr_conv<<<8192, 256, 0, stream>>>(wcatT, em_w1, 2048, 1024, 1024);
    tr_conv<<<8192, 256, 0, stream>>>(wcatT + (size_t)1024 * 2048, es_w1, 2048, 1024, 1024);
    tr_conv<<<512, 256, 0, stream>>>(emW2T, em_w2, 1024, 128, 128);
    tr_conv<<<512, 256, 0, stream>>>(esW2T, es_w2, 1024, 128, 128);
    tr_conv<<<12288, 256, 0, stream>>>(wihPhiT, gwih, 1024, 3072, 3072);
    tr_conv<<<1536, 256, 0, stream>>>(wihZT, gwih + (size_t)1024 * 3072, 128, 3072, 3072);
    tr_conv<<<4096, 256, 0, stream>>>(pmW1T, pm_w1, 1024, 1024, 1024);
    tr_conv<<<512, 256, 0, stream>>>(pmW2T, pm_w2, 1024, 128, 128);
    tr_conv<<<4096, 256, 0, stream>>>(psW1T, ps_w1, 1024, 1024, 1024);
    tr_conv<<<512, 256, 0, stream>>>(psW2T, ps_w2, 1024, 128, 128);
    tr_conv<<<4608, 256, 0, stream>>>(dmW1T, dm_w1, 1152, 1024, 1024);
    tr_conv<<<2048, 256, 0, stream>>>(dmW2T, dm_w2, 1024, 512, 512);

    // PHI = relu(x_t @ phix_w + b)  [T*B, 1024]
    gemm128<EPI_BF16_RELU><<<dim3(8, 512, 1), 256, 0, stream>>>(
        XbfT, nullptr, 512, 0, 512, phixWt, 512, phix_b, PHI, nullptr, 65536, 1024, 512, 512);

    // ---- phase B: 256 sequential steps (GIP chunked by 32 steps) ----
    for (int c = 0; c < 8; c++) {
        // GIP chunk = PHI[c] @ gru_wih[:H]  [8192, 3072]
        gemm128<EPI_BF16_NONE><<<dim3(24, 64, 1), 256, 0, stream>>>(
            PHI + (size_t)c * 8388608, nullptr, 1024, 0, 1024, wihPhiT, 1024, nullptr,
            GIPC, nullptr, 8192, 3072, 1024, 1024);
        for (int k = 0; k < 32; k++) {
            const int t = c * 32 + k;
            // T12 partials = [h_t | phi_t] @ [em_w1 ; es_w1]  split-K=8
            gemm128<EPI_PARTIAL><<<dim3(16, 2, 8), 256, 0, stream>>>(
                HS + (size_t)t * 262144, PHI + (size_t)t * 262144, 1024, 1024, 1024,
                wcatT, 2048, nullptr, nullptr, PBUF, 256, 2048, 2048, 256);
            step_zg<<<256, 1024, 0, stream>>>(
                PBUF, em_b1, es_b1, emW2T, esW2T, em_b2, es_b2,
                eps + (size_t)t * 32768,
                wihZT, GIPC + (size_t)k * 786432, gbih, gbhh,
                out + O_Z + (size_t)t * 32768, out + O_MU + (size_t)t * 32768,
                out + O_STD + (size_t)t * 32768,
                ZBF + (size_t)t * 32768, HS + (size_t)(t + 1) * 262144);
        }
    }

    // ---- phase C: deferred prior / decoder / loss ----
    gemm128<EPI_BF16_RELU><<<dim3(8, 512, 1), 256, 0, stream>>>(
        HS, nullptr, 1024, 0, 1024, pmW1T, 1024, pm_b1, PHI, nullptr, 65536, 1024, 1024, 1024);
    gemm128<EPI_F32_RELU><<<dim3(1, 512, 1), 256, 0, stream>>>(
        PHI, nullptr, 1024, 0, 1024, pmW2T, 1024, pm_b2, nullptr, PMbuf, 65536, 128, 1024, 1024);
    gemm128<EPI_BF16_RELU><<<dim3(8, 512, 1), 256, 0, stream>>>(
        HS, nullptr, 1024, 0, 1024, psW1T, 1024, ps_b1, PHI, nullptr, 65536, 1024, 1024, 1024);
    gemm128<EPI_F32_SP><<<dim3(1, 512, 1), 256, 0, stream>>>(
        PHI, nullptr, 1024, 0, 1024, psW2T, 1024, ps_b2, nullptr, PSbuf, 65536, 128, 1024, 1024);
    // decoder: [h_t | z_t] @ dm_w1 (dual-A, kSplit=1024), then sigmoid layer -> dec_mu
    gemm128<EPI_BF16_RELU><<<dim3(8, 512, 1), 256, 0, stream>>>(
        HS, ZBF, 1024, 128, 1024, dmW1T, 1152, dm_b1, PHI, nullptr, 65536, 1024, 1152, 1152);
    gemm128<EPI_F32_SIG><<<dim3(4, 512, 1), 256, 0, stream>>>(
        PHI, nullptr, 1024, 0, 1024, dmW2T, 1024, dm_b2, nullptr, out + O_XM, 65536, 512, 1024, 1024);

    loss_per_t<<<256, 256, 0, stream>>>(x, out + O_XM, out + O_MU, out + O_STD,
                                        PMbuf, PSbuf, kldT, nllT);
    loss_final<<<1, 256, 0, stream>>>(kldT, nllT, out);
}